// Round 6
// baseline (291.136 us; speedup 1.0000x reference)
//
#include <hip/hip_runtime.h>
#include <cstdint>
#include <cstddef>

// Problem constants
#define B_   4
#define S_   4096
#define H_   1024
#define NH_  16
#define D_   64
#define M_TOT (B_ * S_)    // 16384 rows of hidden
#define K_TOT H_           // 1024 reduction dim
#define N_TOT (3 * H_)     // 3072 = concat(Q,K,V) output cols
#define SCALE_ 0.125f      // 1/sqrt(64)
#define NCH 16             // chunks for global-attention online softmax
#define CH (S_ / NCH)      // 256 positions per chunk

typedef __bf16 bf16x8 __attribute__((ext_vector_type(8)));
typedef float  f32x4  __attribute__((ext_vector_type(4)));
typedef float  f32x16 __attribute__((ext_vector_type(16)));

__device__ __forceinline__ unsigned short f2b(float x) {
    unsigned int u = __float_as_uint(x);
    u += 0x7FFFu + ((u >> 16) & 1u);          // round-to-nearest-even
    return (unsigned short)(u >> 16);
}
__device__ __forceinline__ float b2f(unsigned int u) {   // u = bf16 bits in low 16
    return __uint_as_float(u << 16);
}
__device__ __forceinline__ void unp8(uint4 u, float* f) {
    f[0] = b2f(u.x & 0xffffu); f[1] = b2f(u.x >> 16);
    f[2] = b2f(u.y & 0xffffu); f[3] = b2f(u.y >> 16);
    f[4] = b2f(u.z & 0xffffu); f[5] = b2f(u.z >> 16);
    f[6] = b2f(u.w & 0xffffu); f[7] = b2f(u.w >> 16);
}
__device__ __forceinline__ unsigned int pack2(float lo, float hi) {
    return (unsigned int)f2b(lo) | ((unsigned int)f2b(hi) << 16);
}

// ------------------------------------------------- fused fp32->bf16 converts
__global__ __launch_bounds__(256) void cvt_all(const float* __restrict__ hs,
                                               const float* __restrict__ wq,
                                               const float* __restrict__ wk,
                                               const float* __restrict__ wv,
                                               unsigned short* __restrict__ Xb,
                                               unsigned short* __restrict__ Wb) {
    const int i = blockIdx.x * 256 + threadIdx.x;
    const int X8 = M_TOT * K_TOT / 8;          // 2097152 = 2^21
    const float4* sp;
    uint4* dp;
    int off;
    if (i < X8) {
        sp = (const float4*)hs;
        dp = (uint4*)Xb;
        off = i;
    } else {
        const int j = i - X8;
        const int w = j >> 17;                 // H*H/8 = 2^17
        off = j & 0x1ffff;
        sp = (const float4*)((w == 0) ? wq : (w == 1 ? wk : wv));
        dp = (uint4*)(Wb + (size_t)w * H_ * H_);
    }
    const float4 v0 = sp[off * 2];
    const float4 v1 = sp[off * 2 + 1];
    uint4 o;
    o.x = pack2(v0.x, v0.y);
    o.y = pack2(v0.z, v0.w);
    o.z = pack2(v1.x, v1.y);
    o.w = pack2(v1.z, v1.w);
    dp[off] = o;
}

// ---------------------------------------------------------------- QKV GEMM
// Round 9: same 256x256 / BK=64 / 8-wave / 2-buf / 4-phase / counted-vmcnt(6)
// skeleton as R7 (verified 122us), with the MFMA shape switched
// 16x16x32 -> 32x32x16 (m119: 2495 vs 2176 TF pipe ceiling; half the issue
// slots for the same FLOPs). Per wave 128x64 = 4 m-subtiles x 2 n-subtiles of
// 32x32; K-tile = 4 ks-steps of K=16. Phase mapping unchanged:
//   d0: 12 ds_reads (A msub0-1, B nsub0) + STAGE_A(t+1,1) + 8 MFMA
//   d1:  4 ds_reads (B nsub1)                             + 8 MFMA
//   d2:  8 ds_reads (A msub2-3) + STAGE_B(t+2,0/1)        + 8 MFMA
//   d3:  STAGE_A(t+2,0)                                   + 8 MFMA + vmcnt(6)
// Stored LDS layout + staging involution identical to R7 (bank-uniform for the
// new read pattern: 8 word-accesses/bank, all 64 lane addrs distinct).
// C-layout (m74/m101 verified): col=lane&31, row=(reg&3)+8*(reg>>2)+4*(lane>>5).
__global__ __launch_bounds__(512) void gemm_qkv(const unsigned short* __restrict__ A,
                                                const unsigned short* __restrict__ W,
                                                const float* __restrict__ bq,
                                                const float* __restrict__ bk,
                                                const float* __restrict__ bv,
                                                unsigned short* __restrict__ C) {
    __shared__ unsigned short Asl[2][256 * 64] __attribute__((aligned(16)));
    __shared__ unsigned short Bsl[2][256 * 64] __attribute__((aligned(16)));

    const int tid  = threadIdx.x;
    const int wid  = tid >> 6;
    const int lane = tid & 63;
    const int wm = wid >> 2, wn = wid & 3;     // 2 x 4 wave grid

    // XCD-aware bijective swizzle: 768 blocks = 8 XCDs x 96
    const int wg = (blockIdx.x & 7) * 96 + (blockIdx.x >> 3);
    const int bx = wg % 12;                    // N tile (3072/256)
    const int by = wg / 12;                    // M tile (16384/256)
    const int m0 = by * 256;
    const int n0 = bx * 256;

    // staging: one 8KB load = 64 rows x 128B; thread -> 16B slot; involution on k.
    // stored at (row, H, S): global kk-half = H ^ ((row>>2)&1), 8-chunk = S ^ (row&3)
    const int srow = tid >> 3;
    const int gk = ((((tid >> 2) & 1) ^ ((tid >> 5) & 1)) << 5)
                 + (((tid & 3) ^ ((tid >> 3) & 3)) << 3);
    const size_t aG = (size_t)(m0 + srow) * K_TOT + gk;
    const size_t bG = (size_t)(n0 + srow) * K_TOT + gk;
    const int ldsW = wid << 9;                 // wave-uniform: rows wid*8 -> wid*8*64

    auto ST = [&](const unsigned short* g, unsigned short* l) {
        __builtin_amdgcn_global_load_lds((const __attribute__((address_space(1))) void*)g,
                                         (__attribute__((address_space(3))) void*)l, 16, 0, 0);
    };
    auto STAGE_A = [&](int t, int h) {         // half h of A K-tile t -> buf t&1
        unsigned short* l = &Asl[t & 1][(h << 13) + ldsW];
        const unsigned short* g = A + aG + ((size_t)(h << 7)) * K_TOT + (size_t)t * 64;
        ST(g, l);
        ST(g + (size_t)64 * K_TOT, l + 4096);
    };
    auto STAGE_B = [&](int t, int h) {
        unsigned short* l = &Bsl[t & 1][(h << 13) + ldsW];
        const unsigned short* g = W + bG + ((size_t)(h << 7)) * K_TOT + (size_t)t * 64;
        ST(g, l);
        ST(g + (size_t)64 * K_TOT, l + 4096);
    };

    // ---- 32x32 fragment-read constants (inverse involution).
    // lane l: row r5 = l&31, k-span = gc*8 with gc = ks*2 + (l>>5).
    // slot: S = (gc&3)^(r5&3), H = (gc>>2)^((r5>>2)&1)  (row bits indep. of subtile)
    const int r5 = lane & 31;
    const int hi = lane >> 5;
    const int s0 = (hi ^ (r5 & 3)) << 3;           // S-slot (ushort off) for ks=0
    const int s2 = s0 ^ 16;                        // for gc&3 = 2+hi
    const int h0 = ((r5 >> 2) & 1) << 5;           // H-slot for gc>>2 = 0
    const int h1 = h0 ^ 32;
    const int ck[4] = { h0 + s0, h0 + s2, h1 + s0, h1 + s2 };   // per-ks chunk offset
    const int arow = (wm * 128 + r5) * 64;         // + msub*2048
    const int brow = (wn * 64  + r5) * 64;         // + nsub*2048

    f32x16 acc[4][2];
#pragma unroll
    for (int i = 0; i < 4; i++)
#pragma unroll
        for (int j = 0; j < 2; j++) acc[i][j] = (f32x16){0.f};

    // one K=64 tile, 4 phases, NO sched_barrier pins (m141 lesson)
    auto TILE = [&](int t, bool stD0, bool stD23, int vm) {
        const unsigned short* Ab = Asl[t & 1];
        const unsigned short* Bb = Bsl[t & 1];
        bf16x8 aF[2][4], aG2[2][4], b0[4], b1[4];
        // ---------- d0: 12 reads (A msub0-1, B nsub0) + stage A1(t+1) + 8 MFMA
#pragma unroll
        for (int m = 0; m < 2; m++)
#pragma unroll
            for (int ks = 0; ks < 4; ks++)
                aF[m][ks] = *(const bf16x8*)&Ab[arow + m * 2048 + ck[ks]];
#pragma unroll
        for (int ks = 0; ks < 4; ks++)
            b0[ks] = *(const bf16x8*)&Bb[brow + ck[ks]];
        if (stD0) STAGE_A(t + 1, 1);
        __builtin_amdgcn_s_barrier();
        asm volatile("s_waitcnt lgkmcnt(0)" ::: "memory");
        __builtin_amdgcn_s_setprio(1);
#pragma unroll
        for (int m = 0; m < 2; m++)
#pragma unroll
            for (int ks = 0; ks < 4; ks++)
                acc[m][0] = __builtin_amdgcn_mfma_f32_32x32x16_bf16(aF[m][ks], b0[ks], acc[m][0], 0, 0, 0);
        __builtin_amdgcn_s_setprio(0);
        __builtin_amdgcn_s_barrier();
        // ---------- d1: 4 reads (B nsub1) + 8 MFMA
#pragma unroll
        for (int ks = 0; ks < 4; ks++)
            b1[ks] = *(const bf16x8*)&Bb[brow + 2048 + ck[ks]];
        __builtin_amdgcn_s_barrier();
        asm volatile("s_waitcnt lgkmcnt(0)" ::: "memory");
        __builtin_amdgcn_s_setprio(1);
#pragma unroll
        for (int m = 0; m < 2; m++)
#pragma unroll
            for (int ks = 0; ks < 4; ks++)
                acc[m][1] = __builtin_amdgcn_mfma_f32_32x32x16_bf16(aF[m][ks], b1[ks], acc[m][1], 0, 0, 0);
        __builtin_amdgcn_s_setprio(0);
        __builtin_amdgcn_s_barrier();
        // ---------- d2: 8 reads (A msub2-3) + stage B0,B1(t+2) + 8 MFMA
#pragma unroll
        for (int m = 0; m < 2; m++)
#pragma unroll
            for (int ks = 0; ks < 4; ks++)
                aG2[m][ks] = *(const bf16x8*)&Ab[arow + (m + 2) * 2048 + ck[ks]];
        if (stD23) { STAGE_B(t + 2, 0); STAGE_B(t + 2, 1); }
        __builtin_amdgcn_s_barrier();
        asm volatile("s_waitcnt lgkmcnt(0)" ::: "memory");
        __builtin_amdgcn_s_setprio(1);
#pragma unroll
        for (int m = 0; m < 2; m++)
#pragma unroll
            for (int ks = 0; ks < 4; ks++)
                acc[m + 2][1] = __builtin_amdgcn_mfma_f32_32x32x16_bf16(aG2[m][ks], b1[ks], acc[m + 2][1], 0, 0, 0);
        __builtin_amdgcn_s_setprio(0);
        __builtin_amdgcn_s_barrier();
        // ---------- d3: stage A0(t+2) + 8 MFMA + boundary vmcnt
        if (stD23) STAGE_A(t + 2, 0);
        __builtin_amdgcn_s_barrier();
        __builtin_amdgcn_s_setprio(1);
#pragma unroll
        for (int m = 0; m < 2; m++)
#pragma unroll
            for (int ks = 0; ks < 4; ks++)
                acc[m + 2][0] = __builtin_amdgcn_mfma_f32_32x32x16_bf16(aG2[m][ks], b0[ks], acc[m + 2][0], 0, 0, 0);
        __builtin_amdgcn_s_setprio(0);
        if (vm == 6)      asm volatile("s_waitcnt vmcnt(6)" ::: "memory");
        else if (vm == 0) asm volatile("s_waitcnt vmcnt(0)" ::: "memory");
        if (vm >= 0) __builtin_amdgcn_s_barrier();
    };

    // prologue: tile 0 complete (8 loads) + B0(1),B1(1),A0(1) (6 loads);
    // vmcnt(6) retires exactly the oldest 8 = tile 0. A1(1) staged at d0 of tile 0.
    STAGE_A(0, 0); STAGE_A(0, 1); STAGE_B(0, 0); STAGE_B(0, 1);
    STAGE_B(1, 0); STAGE_B(1, 1); STAGE_A(1, 0);
    asm volatile("s_waitcnt vmcnt(6)" ::: "memory");
    __builtin_amdgcn_s_barrier();

    // 16 K-tiles: 14 full + 2 tail. Unroll-2 makes buf index t&1 compile-time.
#pragma unroll 1
    for (int tt = 0; tt < 14; tt += 2) {
        TILE(tt,     true, true, 6);
        TILE(tt + 1, true, true, 6);
    }
    TILE(14, true,  false, 0);   // stages A1(15); drain all before last tile
    TILE(15, false, false, -1);

    // C write + bias. 32x32 C layout (m74/m101): col=lane&31,
    // row = (j&3) + 8*(j>>2) + 4*(lane>>5), j in [0,16).
    const int cl = lane & 31;
    const int rb4 = 4 * hi;
#pragma unroll
    for (int ms = 0; ms < 4; ms++) {
#pragma unroll
        for (int ns = 0; ns < 2; ns++) {
            const int gc = n0 + wn * 64 + ns * 32 + cl;
            const float bias = (gc < H_) ? bq[gc] : (gc < 2 * H_ ? bk[gc - H_] : bv[gc - 2 * H_]);
#pragma unroll
            for (int j = 0; j < 16; j++) {
                const int gr = m0 + wm * 128 + ms * 32 + (j & 3) + 8 * (j >> 2) + rb4;
                C[(size_t)gr * N_TOT + gc] = f2b(acc[ms][ns][j] + bias);
            }
        }
    }
}

// ------------------------------------------------- fused attention
// gattn chunk-blocks and local-attention blocks are mutually independent (both
// only read QKV) and share ONE kernel. grid (B*NH, 144):
//   y in [0,128)   -> local attention for 32 s-positions
//   y in [128,144) -> global-attention chunk y-128
__global__ __launch_bounds__(256) void attn_fused(const unsigned short* __restrict__ QKV,
                                                  const float* __restrict__ mask,
                                                  float* __restrict__ ctx,
                                                  float* __restrict__ lat,
                                                  float* __restrict__ Pm,
                                                  float* __restrict__ Pl,
                                                  float* __restrict__ Po) {
    const int bh = blockIdx.x;
    const int b = bh >> 4, h = bh & 15;

    if (blockIdx.y >= 128) {
        // ------------------------------ global attention partial (one chunk)
        const int chunk = blockIdx.y - 128;
        const int tid = threadIdx.x;
        const int w = tid >> 6, lane = tid & 63;

        __shared__ float gq_sh[D_];
        __shared__ float pr[CH];
        __shared__ float red[8];
        __shared__ float osum[4][D_];

        const unsigned short* gqp = QKV + (size_t)(b * S_) * N_TOT + h * D_;
        if (tid < D_) gq_sh[tid] = b2f(gqp[tid]);
        __syncthreads();

        const int s0 = chunk * CH;
        const int s  = s0 + tid;
        const uint4* kp4 = (const uint4*)(QKV + (size_t)(b * S_ + s) * N_TOT + H_ + h * D_);
        float acc = 0.f;
#pragma unroll
        for (int c = 0; c < 8; c++) {
            uint4 r = kp4[c];
            acc += b2f(r.x & 0xffffu) * gq_sh[c * 8 + 0];
            acc += b2f(r.x >> 16)     * gq_sh[c * 8 + 1];
            acc += b2f(r.y & 0xffffu) * gq_sh[c * 8 + 2];
            acc += b2f(r.y >> 16)     * gq_sh[c * 8 + 3];
            acc += b2f(r.z & 0xffffu) * gq_sh[c * 8 + 4];
            acc += b2f(r.z >> 16)     * gq_sh[c * 8 + 5];
            acc += b2f(r.w & 0xffffu) * gq_sh[c * 8 + 6];
            acc += b2f(r.w >> 16)     * gq_sh[c * 8 + 7];
        }
        const float sv = acc * SCALE_ + mask[b * S_ + s];

        float wmax = sv;
#pragma unroll
        for (int m = 32; m >= 1; m >>= 1) wmax = fmaxf(wmax, __shfl_xor(wmax, m, 64));
        if (lane == 0) red[w] = wmax;
        __syncthreads();
        const float bmax = fmaxf(fmaxf(red[0], red[1]), fmaxf(red[2], red[3]));

        const float p = __expf(sv - bmax);
        pr[tid] = p;
        float wsum = p;
#pragma unroll
        for (int m = 32; m >= 1; m >>= 1) wsum += __shfl_xor(wsum, m, 64);
        if (lane == 0) red[4 + w] = wsum;
        __syncthreads();   // publishes pr[] for phase 2
        const float bsum = red[4] + red[5] + red[6] + red[7];

        const int g = lane >> 3;
        const int l = lane & 7;
        float o8[8];
#pragma unroll
        for (int j = 0; j < 8; j++) o8[j] = 0.f;
        const int sbase = s0 + w * 64;
#pragma unroll
        for (int i = 0; i < 8; i++) {
            const int si = sbase + i * 8 + g;
            const uint4 vu = *(const uint4*)(QKV + (size_t)(b * S_ + si) * N_TOT + 2 * H_ + h * D_ + l * 8);
            float vf[8];
            unp8(vu, vf);
            const float pw = pr[w * 64 + i * 8 + g];
#pragma unroll
            for (int j = 0; j < 8; j++) o8[j] += pw * vf[j];
        }
#pragma unroll
        for (int j = 0; j < 8; j++) {
            o8[j] += __shfl_xor(o8[j], 8, 64);
            o8[j] += __shfl_xor(o8[j], 16, 64);
            o8[j] += __shfl_xor(o8[j], 32, 64);
        }
        if (g == 0) {
#pragma unroll
            for (int j = 0; j < 8; j++) osum[w][l * 8 + j] = o8[j];
        }
        __syncthreads();
        if (tid < D_) {
            const float ot = osum[0][tid] + osum[1][tid] + osum[2][tid] + osum[3][tid];
            Po[(size_t)(bh * NCH + chunk) * D_ + tid] = ot;
            if (tid == 0) {
                Pm[bh * NCH + chunk] = bmax;
                Pl[bh * NCH + chunk] = bsum;
            }
        }
        return;
    }

    // ------------------------------ local attention (32 s-positions per block)
    const int w = threadIdx.x >> 6, lane = threadIdx.x & 63;
    const int g = lane >> 3;     // s-subgroup within wave
    const int l = lane & 7;      // d-octet index
    const int s = 1 + blockIdx.y * 32 + w * 8 + g;
    if (s >= S_) return;         // only the very last 8-lane group; no barriers here

    const size_t rowS = (size_t)(b * S_ + s) * N_TOT + h * D_ + l * 8;
    const size_t row0 = (size_t)(b * S_) * N_TOT + h * D_ + l * 8;

    uint4 qu  = *(const uint4*)(QKV + rowS);
    uint4 ku  = *(const uint4*)(QKV + rowS + H_);
    uint4 k0u = *(const uint4*)(QKV + row0 + H_);
    float qf[8], kf[8], k0f[8];
    unp8(qu, qf); unp8(ku, kf); unp8(k0u, k0f);

    float ps = 0.f, pg = 0.f;
#pragma unroll
    for (int i = 0; i < 8; i++) { ps += qf[i] * kf[i]; pg += qf[i] * k0f[i]; }
#pragma unroll
    for (int m = 1; m < 8; m <<= 1) {   // reduce within the 8-lane d-group
        ps += __shfl_xor(ps, m, 64);
        pg += __shfl_xor(pg, m, 64);
    }
    ps *= SCALE_; pg *= SCALE_;
    const float mx = fmaxf(ps, pg);
    const float e0 = __expf(ps - mx), e1 = __expf(pg - mx);
    const float z = e0 + e1;
    const float p0 = e0 / z, p1 = e1 / z;

    uint4 vu  = *(const uint4*)(QKV + rowS + 2 * H_);
    uint4 v0u = *(const uint4*)(QKV + row0 + 2 * H_);
    float vf[8], v0f[8];
    unp8(vu, vf); unp8(v0u, v0f);

    float* cp = ctx + (size_t)b * (S_ * H_) + (size_t)s * H_ + h * D_ + l * 8;
    float4 o0, o1;
    o0.x = p0 * vf[0] + p1 * v0f[0];
    o0.y = p0 * vf[1] + p1 * v0f[1];
    o0.z = p0 * vf[2] + p1 * v0f[2];
    o0.w = p0 * vf[3] + p1 * v0f[3];
    o1.x = p0 * vf[4] + p1 * v0f[4];
    o1.y = p0 * vf[5] + p1 * v0f[5];
    o1.z = p0 * vf[6] + p1 * v0f[6];
    o1.w = p0 * vf[7] + p1 * v0f[7];
    ((float4*)cp)[0] = o0;
    ((float4*)cp)[1] = o1;

    if (l == 0) {
        float2 lp; lp.x = p0; lp.y = p1;
        ((float2*)(lat + ((size_t)bh * (S_ - 1) + (s - 1)) * 2))[0] = lp;
    }
}

// ------------------------------------------------- global-attention combine
// 64 blocks x 1 wave: block bh combines its NCH partials into ctx row s=0.
__global__ __launch_bounds__(64) void gcombine(const float* __restrict__ Pm,
                                               const float* __restrict__ Pl,
                                               const float* __restrict__ Po,
                                               float* __restrict__ ctx) {
    const int bh = blockIdx.x;
    const int b = bh >> 4, h = bh & 15;
    const int d = threadIdx.x;
    float ms = -1e30f;
#pragma unroll
    for (int c = 0; c < NCH; c++) ms = fmaxf(ms, Pm[bh * NCH + c]);
    float z = 0.f, o = 0.f;
#pragma unroll
    for (int c = 0; c < NCH; c++) {
        const float e = __expf(Pm[bh * NCH + c] - ms);
        z += Pl[bh * NCH + c] * e;
        o += Po[(size_t)(bh * NCH + c) * D_ + d] * e;
    }
    ctx[(size_t)b * S_ * H_ + (size_t)h * D_ + d] = o / z;
}

// ---------------------------------------------------------------- launcher
extern "C" void kernel_launch(void* const* d_in, const int* in_sizes, int n_in,
                              void* d_out, int out_size, void* d_ws, size_t ws_size,
                              hipStream_t stream) {
    const float* hs   = (const float*)d_in[0];
    const float* mask = (const float*)d_in[1];
    const float* Wq   = (const float*)d_in[2];
    const float* bq   = (const float*)d_in[3];
    const float* Wk   = (const float*)d_in[4];
    const float* bk   = (const float*)d_in[5];
    const float* Wv   = (const float*)d_in[6];
    const float* bv   = (const float*)d_in[7];

    float* out = (float*)d_out;                       // (B,S,H) fp32
    float* lat = out + (size_t)B_ * S_ * H_;          // (B,NH,S-1,1,2) fp32

    char* ws = (char*)d_ws;
    const size_t offXb  = 0;
    const size_t offWb  = offXb  + (size_t)M_TOT * K_TOT * 2;
    const size_t offQKV = offWb  + (size_t)3 * H_ * H_ * 2;
    const size_t offPm  = offQKV + (size_t)M_TOT * N_TOT * 2;
    const size_t offPl  = offPm  + (size_t)B_ * NH_ * NCH * 4;
    const size_t offPo  = offPl  + (size_t)B_ * NH_ * NCH * 4;

    unsigned short* Xb  = (unsigned short*)(ws + offXb);
    unsigned short* Wb  = (unsigned short*)(ws + offWb);
    unsigned short* QKV = (unsigned short*)(ws + offQKV);
    float* Pm = (float*)(ws + offPm);
    float* Pl = (float*)(ws + offPl);
    float* Po = (float*)(ws + offPo);

    const int total8 = M_TOT * K_TOT / 8 + 3 * H_ * H_ / 8;   // 2490368, /256 exact
    hipLaunchKernelGGL(cvt_all, dim3(total8 / 256), dim3(256), 0, stream,
                       hs, Wq, Wk, Wv, Xb, Wb);
    hipLaunchKernelGGL(gemm_qkv, dim3(12 * 64), dim3(512), 0, stream,
                       Xb, Wb, bq, bk, bv, QKV);
    hipLaunchKernelGGL(attn_fused, dim3(B_ * NH_, 144), dim3(256), 0, stream,
                       QKV, mask, out, lat, Pm, Pl, Po);
    hipLaunchKernelGGL(gcombine, dim3(B_ * NH_), dim3(64), 0, stream, Pm, Pl, Po, out);
}

// Round 7
// 290.604 us; speedup vs baseline: 1.0018x; 1.0018x over previous
//
#include <hip/hip_runtime.h>
#include <cstdint>
#include <cstddef>

// Problem constants
#define B_   4
#define S_   4096
#define H_   1024
#define NH_  16
#define D_   64
#define M_TOT (B_ * S_)    // 16384 rows of hidden
#define K_TOT H_           // 1024 reduction dim
#define N_TOT (3 * H_)     // 3072 = concat(Q,K,V) output cols
#define SCALE_ 0.125f      // 1/sqrt(64)
#define NCH 16             // chunks for global-attention online softmax
#define CH (S_ / NCH)      // 256 positions per chunk

typedef __bf16 bf16x8 __attribute__((ext_vector_type(8)));
typedef float  f32x4  __attribute__((ext_vector_type(4)));
typedef float  f32x16 __attribute__((ext_vector_type(16)));

__device__ __forceinline__ unsigned short f2b(float x) {
    unsigned int u = __float_as_uint(x);
    u += 0x7FFFu + ((u >> 16) & 1u);          // round-to-nearest-even
    return (unsigned short)(u >> 16);
}
__device__ __forceinline__ float b2f(unsigned int u) {   // u = bf16 bits in low 16
    return __uint_as_float(u << 16);
}
__device__ __forceinline__ void unp8(uint4 u, float* f) {
    f[0] = b2f(u.x & 0xffffu); f[1] = b2f(u.x >> 16);
    f[2] = b2f(u.y & 0xffffu); f[3] = b2f(u.y >> 16);
    f[4] = b2f(u.z & 0xffffu); f[5] = b2f(u.z >> 16);
    f[6] = b2f(u.w & 0xffffu); f[7] = b2f(u.w >> 16);
}
__device__ __forceinline__ unsigned int pack2(float lo, float hi) {
    return (unsigned int)f2b(lo) | ((unsigned int)f2b(hi) << 16);
}

// ------------------------------------------------- fused fp32->bf16 converts
__global__ __launch_bounds__(256) void cvt_all(const float* __restrict__ hs,
                                               const float* __restrict__ wq,
                                               const float* __restrict__ wk,
                                               const float* __restrict__ wv,
                                               unsigned short* __restrict__ Xb,
                                               unsigned short* __restrict__ Wb) {
    const int i = blockIdx.x * 256 + threadIdx.x;
    const int X8 = M_TOT * K_TOT / 8;          // 2097152 = 2^21
    const float4* sp;
    uint4* dp;
    int off;
    if (i < X8) {
        sp = (const float4*)hs;
        dp = (uint4*)Xb;
        off = i;
    } else {
        const int j = i - X8;
        const int w = j >> 17;                 // H*H/8 = 2^17
        off = j & 0x1ffff;
        sp = (const float4*)((w == 0) ? wq : (w == 1 ? wk : wv));
        dp = (uint4*)(Wb + (size_t)w * H_ * H_);
    }
    const float4 v0 = sp[off * 2];
    const float4 v1 = sp[off * 2 + 1];
    uint4 o;
    o.x = pack2(v0.x, v0.y);
    o.y = pack2(v0.z, v0.w);
    o.z = pack2(v1.x, v1.y);
    o.w = pack2(v1.z, v1.w);
    dp[off] = o;
}

// ---------------------------------------------------------------- QKV GEMM
// Round 10: R9's 32x32x16 skeleton with the LDS involution RE-KEYED to
// replicate the empirically-zero-conflict lane sequence (R2/R7 family):
//   stored (row, H, S) holds global (kk = H ^ (row&1), ch = S ^ ((row>>1)&3))
// (R9 keyed H on (row>>2)&1 / S on row&3 -> 9.4M conflicts, the exact R1-class
// count = +4 cyc on every ds_read_b128. Consecutive-lane byte offsets mod 128
// now follow {0,64,16,80,32,96,48,112} — byte-identical to the measured-zero
// pattern. Same involution applied on the staging SOURCE address (rule #21);
// DMA LDS writes stay linear and are unaffected.)
// Everything else (256x256 / BK=64 / 8-wave / 2-buf / 4-phase / vmcnt(6) /
// 32x32x16 MFMA / C-layout) identical to R9, which passed correctness.
__global__ __launch_bounds__(512) void gemm_qkv(const unsigned short* __restrict__ A,
                                                const unsigned short* __restrict__ W,
                                                const float* __restrict__ bq,
                                                const float* __restrict__ bk,
                                                const float* __restrict__ bv,
                                                unsigned short* __restrict__ C) {
    __shared__ unsigned short Asl[2][256 * 64] __attribute__((aligned(16)));
    __shared__ unsigned short Bsl[2][256 * 64] __attribute__((aligned(16)));

    const int tid  = threadIdx.x;
    const int wid  = tid >> 6;
    const int lane = tid & 63;
    const int wm = wid >> 2, wn = wid & 3;     // 2 x 4 wave grid

    // XCD-aware bijective swizzle: 768 blocks = 8 XCDs x 96
    const int wg = (blockIdx.x & 7) * 96 + (blockIdx.x >> 3);
    const int bx = wg % 12;                    // N tile (3072/256)
    const int by = wg / 12;                    // M tile (16384/256)
    const int m0 = by * 256;
    const int n0 = bx * 256;

    // staging: one 8KB load = 64 rows x 128B; thread -> 16B slot.
    // row = tid>>3, Hs = (tid>>2)&1, Ss = tid&3. NEW involution:
    //   kk = Hs ^ (row&1)        = ((tid>>2)&1) ^ ((tid>>3)&1)
    //   ch = Ss ^ ((row>>1)&3)   = (tid&3) ^ ((tid>>4)&3)
    const int srow = tid >> 3;
    const int gk = ((((tid >> 2) & 1) ^ ((tid >> 3) & 1)) << 5)
                 + (((tid & 3) ^ ((tid >> 4) & 3)) << 3);
    const size_t aG = (size_t)(m0 + srow) * K_TOT + gk;
    const size_t bG = (size_t)(n0 + srow) * K_TOT + gk;
    const int ldsW = wid << 9;                 // wave-uniform: rows wid*8 -> wid*8*64

    auto ST = [&](const unsigned short* g, unsigned short* l) {
        __builtin_amdgcn_global_load_lds((const __attribute__((address_space(1))) void*)g,
                                         (__attribute__((address_space(3))) void*)l, 16, 0, 0);
    };
    auto STAGE_A = [&](int t, int h) {         // half h of A K-tile t -> buf t&1
        unsigned short* l = &Asl[t & 1][(h << 13) + ldsW];
        const unsigned short* g = A + aG + ((size_t)(h << 7)) * K_TOT + (size_t)t * 64;
        ST(g, l);
        ST(g + (size_t)64 * K_TOT, l + 4096);
    };
    auto STAGE_B = [&](int t, int h) {
        unsigned short* l = &Bsl[t & 1][(h << 13) + ldsW];
        const unsigned short* g = W + bG + ((size_t)(h << 7)) * K_TOT + (size_t)t * 64;
        ST(g, l);
        ST(g + (size_t)64 * K_TOT, l + 4096);
    };

    // ---- 32x32 fragment-read constants (inverse involution, NEW keying).
    // lane l: row r5 = l&31, global chunk gc = ks*2 + (l>>5), ks in [0,4).
    // slot: S = (gc&3) ^ ((r5>>1)&3), H = (gc>>2) ^ (r5&1).
    // (subtile row-bases are 32-aligned, so (R>>1)&3 == (r5>>1)&3, R&1 == r5&1)
    const int r5 = lane & 31;
    const int hi = lane >> 5;
    const int sK = (r5 >> 1) & 3;
    const int s0 = (hi ^ sK) << 3;                 // S-slot (ushort off) for ks=0,2
    const int s2 = s0 ^ 16;                        // for ks=1,3 (gc&3 = 2+hi)
    const int h0 = (r5 & 1) << 5;                  // H-slot for gc>>2 = 0
    const int h1 = h0 ^ 32;
    const int ck[4] = { h0 + s0, h0 + s2, h1 + s0, h1 + s2 };   // per-ks chunk offset
    const int arow = (wm * 128 + r5) * 64;         // + msub*2048
    const int brow = (wn * 64  + r5) * 64;         // + nsub*2048

    f32x16 acc[4][2];
#pragma unroll
    for (int i = 0; i < 4; i++)
#pragma unroll
        for (int j = 0; j < 2; j++) acc[i][j] = (f32x16){0.f};

    // one K=64 tile, 4 phases, NO sched_barrier pins (m141 lesson)
    auto TILE = [&](int t, bool stD0, bool stD23, int vm) {
        const unsigned short* Ab = Asl[t & 1];
        const unsigned short* Bb = Bsl[t & 1];
        bf16x8 aF[2][4], aG2[2][4], b0[4], b1[4];
        // ---------- d0: 12 reads (A msub0-1, B nsub0) + stage A1(t+1) + 8 MFMA
#pragma unroll
        for (int m = 0; m < 2; m++)
#pragma unroll
            for (int ks = 0; ks < 4; ks++)
                aF[m][ks] = *(const bf16x8*)&Ab[arow + m * 2048 + ck[ks]];
#pragma unroll
        for (int ks = 0; ks < 4; ks++)
            b0[ks] = *(const bf16x8*)&Bb[brow + ck[ks]];
        if (stD0) STAGE_A(t + 1, 1);
        __builtin_amdgcn_s_barrier();
        asm volatile("s_waitcnt lgkmcnt(0)" ::: "memory");
        __builtin_amdgcn_s_setprio(1);
#pragma unroll
        for (int m = 0; m < 2; m++)
#pragma unroll
            for (int ks = 0; ks < 4; ks++)
                acc[m][0] = __builtin_amdgcn_mfma_f32_32x32x16_bf16(aF[m][ks], b0[ks], acc[m][0], 0, 0, 0);
        __builtin_amdgcn_s_setprio(0);
        __builtin_amdgcn_s_barrier();
        // ---------- d1: 4 reads (B nsub1) + 8 MFMA
#pragma unroll
        for (int ks = 0; ks < 4; ks++)
            b1[ks] = *(const bf16x8*)&Bb[brow + 2048 + ck[ks]];
        __builtin_amdgcn_s_barrier();
        asm volatile("s_waitcnt lgkmcnt(0)" ::: "memory");
        __builtin_amdgcn_s_setprio(1);
#pragma unroll
        for (int m = 0; m < 2; m++)
#pragma unroll
            for (int ks = 0; ks < 4; ks++)
                acc[m][1] = __builtin_amdgcn_mfma_f32_32x32x16_bf16(aF[m][ks], b1[ks], acc[m][1], 0, 0, 0);
        __builtin_amdgcn_s_setprio(0);
        __builtin_amdgcn_s_barrier();
        // ---------- d2: 8 reads (A msub2-3) + stage B0,B1(t+2) + 8 MFMA
#pragma unroll
        for (int m = 0; m < 2; m++)
#pragma unroll
            for (int ks = 0; ks < 4; ks++)
                aG2[m][ks] = *(const bf16x8*)&Ab[arow + (m + 2) * 2048 + ck[ks]];
        if (stD23) { STAGE_B(t + 2, 0); STAGE_B(t + 2, 1); }
        __builtin_amdgcn_s_barrier();
        asm volatile("s_waitcnt lgkmcnt(0)" ::: "memory");
        __builtin_amdgcn_s_setprio(1);
#pragma unroll
        for (int m = 0; m < 2; m++)
#pragma unroll
            for (int ks = 0; ks < 4; ks++)
                acc[m + 2][1] = __builtin_amdgcn_mfma_f32_32x32x16_bf16(aG2[m][ks], b1[ks], acc[m + 2][1], 0, 0, 0);
        __builtin_amdgcn_s_setprio(0);
        __builtin_amdgcn_s_barrier();
        // ---------- d3: stage A0(t+2) + 8 MFMA + boundary vmcnt
        if (stD23) STAGE_A(t + 2, 0);
        __builtin_amdgcn_s_barrier();
        __builtin_amdgcn_s_setprio(1);
#pragma unroll
        for (int m = 0; m < 2; m++)
#pragma unroll
            for (int ks = 0; ks < 4; ks++)
                acc[m + 2][0] = __builtin_amdgcn_mfma_f32_32x32x16_bf16(aG2[m][ks], b0[ks], acc[m + 2][0], 0, 0, 0);
        __builtin_amdgcn_s_setprio(0);
        if (vm == 6)      asm volatile("s_waitcnt vmcnt(6)" ::: "memory");
        else if (vm == 0) asm volatile("s_waitcnt vmcnt(0)" ::: "memory");
        if (vm >= 0) __builtin_amdgcn_s_barrier();
    };

    // prologue: tile 0 complete (8 loads) + B0(1),B1(1),A0(1) (6 loads);
    // vmcnt(6) retires exactly the oldest 8 = tile 0. A1(1) staged at d0 of tile 0.
    STAGE_A(0, 0); STAGE_A(0, 1); STAGE_B(0, 0); STAGE_B(0, 1);
    STAGE_B(1, 0); STAGE_B(1, 1); STAGE_A(1, 0);
    asm volatile("s_waitcnt vmcnt(6)" ::: "memory");
    __builtin_amdgcn_s_barrier();

    // 16 K-tiles: 14 full + 2 tail. Unroll-2 makes buf index t&1 compile-time.
#pragma unroll 1
    for (int tt = 0; tt < 14; tt += 2) {
        TILE(tt,     true, true, 6);
        TILE(tt + 1, true, true, 6);
    }
    TILE(14, true,  false, 0);   // stages A1(15); drain all before last tile
    TILE(15, false, false, -1);

    // C write + bias. 32x32 C layout (m74/m101): col=lane&31,
    // row = (j&3) + 8*(j>>2) + 4*(lane>>5), j in [0,16).
    const int cl = lane & 31;
    const int rb4 = 4 * hi;
#pragma unroll
    for (int ms = 0; ms < 4; ms++) {
#pragma unroll
        for (int ns = 0; ns < 2; ns++) {
            const int gc = n0 + wn * 64 + ns * 32 + cl;
            const float bias = (gc < H_) ? bq[gc] : (gc < 2 * H_ ? bk[gc - H_] : bv[gc - 2 * H_]);
#pragma unroll
            for (int j = 0; j < 16; j++) {
                const int gr = m0 + wm * 128 + ms * 32 + (j & 3) + 8 * (j >> 2) + rb4;
                C[(size_t)gr * N_TOT + gc] = f2b(acc[ms][ns][j] + bias);
            }
        }
    }
}

// ------------------------------------------------- fused attention
// gattn chunk-blocks and local-attention blocks are mutually independent (both
// only read QKV) and share ONE kernel. grid (B*NH, 144):
//   y in [0,128)   -> local attention for 32 s-positions
//   y in [128,144) -> global-attention chunk y-128
__global__ __launch_bounds__(256) void attn_fused(const unsigned short* __restrict__ QKV,
                                                  const float* __restrict__ mask,
                                                  float* __restrict__ ctx,
                                                  float* __restrict__ lat,
                                                  float* __restrict__ Pm,
                                                  float* __restrict__ Pl,
                                                  float* __restrict__ Po) {
    const int bh = blockIdx.x;
    const int b = bh >> 4, h = bh & 15;

    if (blockIdx.y >= 128) {
        // ------------------------------ global attention partial (one chunk)
        const int chunk = blockIdx.y - 128;
        const int tid = threadIdx.x;
        const int w = tid >> 6, lane = tid & 63;

        __shared__ float gq_sh[D_];
        __shared__ float pr[CH];
        __shared__ float red[8];
        __shared__ float osum[4][D_];

        const unsigned short* gqp = QKV + (size_t)(b * S_) * N_TOT + h * D_;
        if (tid < D_) gq_sh[tid] = b2f(gqp[tid]);
        __syncthreads();

        const int s0 = chunk * CH;
        const int s  = s0 + tid;
        const uint4* kp4 = (const uint4*)(QKV + (size_t)(b * S_ + s) * N_TOT + H_ + h * D_);
        float acc = 0.f;
#pragma unroll
        for (int c = 0; c < 8; c++) {
            uint4 r = kp4[c];
            acc += b2f(r.x & 0xffffu) * gq_sh[c * 8 + 0];
            acc += b2f(r.x >> 16)     * gq_sh[c * 8 + 1];
            acc += b2f(r.y & 0xffffu) * gq_sh[c * 8 + 2];
            acc += b2f(r.y >> 16)     * gq_sh[c * 8 + 3];
            acc += b2f(r.z & 0xffffu) * gq_sh[c * 8 + 4];
            acc += b2f(r.z >> 16)     * gq_sh[c * 8 + 5];
            acc += b2f(r.w & 0xffffu) * gq_sh[c * 8 + 6];
            acc += b2f(r.w >> 16)     * gq_sh[c * 8 + 7];
        }
        const float sv = acc * SCALE_ + mask[b * S_ + s];

        float wmax = sv;
#pragma unroll
        for (int m = 32; m >= 1; m >>= 1) wmax = fmaxf(wmax, __shfl_xor(wmax, m, 64));
        if (lane == 0) red[w] = wmax;
        __syncthreads();
        const float bmax = fmaxf(fmaxf(red[0], red[1]), fmaxf(red[2], red[3]));

        const float p = __expf(sv - bmax);
        pr[tid] = p;
        float wsum = p;
#pragma unroll
        for (int m = 32; m >= 1; m >>= 1) wsum += __shfl_xor(wsum, m, 64);
        if (lane == 0) red[4 + w] = wsum;
        __syncthreads();   // publishes pr[] for phase 2
        const float bsum = red[4] + red[5] + red[6] + red[7];

        const int g = lane >> 3;
        const int l = lane & 7;
        float o8[8];
#pragma unroll
        for (int j = 0; j < 8; j++) o8[j] = 0.f;
        const int sbase = s0 + w * 64;
#pragma unroll
        for (int i = 0; i < 8; i++) {
            const int si = sbase + i * 8 + g;
            const uint4 vu = *(const uint4*)(QKV + (size_t)(b * S_ + si) * N_TOT + 2 * H_ + h * D_ + l * 8);
            float vf[8];
            unp8(vu, vf);
            const float pw = pr[w * 64 + i * 8 + g];
#pragma unroll
            for (int j = 0; j < 8; j++) o8[j] += pw * vf[j];
        }
#pragma unroll
        for (int j = 0; j < 8; j++) {
            o8[j] += __shfl_xor(o8[j], 8, 64);
            o8[j] += __shfl_xor(o8[j], 16, 64);
            o8[j] += __shfl_xor(o8[j], 32, 64);
        }
        if (g == 0) {
#pragma unroll
            for (int j = 0; j < 8; j++) osum[w][l * 8 + j] = o8[j];
        }
        __syncthreads();
        if (tid < D_) {
            const float ot = osum[0][tid] + osum[1][tid] + osum[2][tid] + osum[3][tid];
            Po[(size_t)(bh * NCH + chunk) * D_ + tid] = ot;
            if (tid == 0) {
                Pm[bh * NCH + chunk] = bmax;
                Pl[bh * NCH + chunk] = bsum;
            }
        }
        return;
    }

    // ------------------------------ local attention (32 s-positions per block)
    const int w = threadIdx.x >> 6, lane = threadIdx.x & 63;
    const int g = lane >> 3;     // s-subgroup within wave
    const int l = lane & 7;      // d-octet index
    const int s = 1 + blockIdx.y * 32 + w * 8 + g;
    if (s >= S_) return;         // only the very last 8-lane group; no barriers here

    const size_t rowS = (size_t)(b * S_ + s) * N_TOT + h * D_ + l * 8;
    const size_t row0 = (size_t)(b * S_) * N_TOT + h * D_ + l * 8;

    uint4 qu  = *(const uint4*)(QKV + rowS);
    uint4 ku  = *(const uint4*)(QKV + rowS + H_);
    uint4 k0u = *(const uint4*)(QKV + row0 + H_);
    float qf[8], kf[8], k0f[8];
    unp8(qu, qf); unp8(ku, kf); unp8(k0u, k0f);

    float ps = 0.f, pg = 0.f;
#pragma unroll
    for (int i = 0; i < 8; i++) { ps += qf[i] * kf[i]; pg += qf[i] * k0f[i]; }
#pragma unroll
    for (int m = 1; m < 8; m <<= 1) {   // reduce within the 8-lane d-group
        ps += __shfl_xor(ps, m, 64);
        pg += __shfl_xor(pg, m, 64);
    }
    ps *= SCALE_; pg *= SCALE_;
    const float mx = fmaxf(ps, pg);
    const float e0 = __expf(ps - mx), e1 = __expf(pg - mx);
    const float z = e0 + e1;
    const float p0 = e0 / z, p1 = e1 / z;

    uint4 vu  = *(const uint4*)(QKV + rowS + 2 * H_);
    uint4 v0u = *(const uint4*)(QKV + row0 + 2 * H_);
    float vf[8], v0f[8];
    unp8(vu, vf); unp8(v0u, v0f);

    float* cp = ctx + (size_t)b * (S_ * H_) + (size_t)s * H_ + h * D_ + l * 8;
    float4 o0, o1;
    o0.x = p0 * vf[0] + p1 * v0f[0];
    o0.y = p0 * vf[1] + p1 * v0f[1];
    o0.z = p0 * vf[2] + p1 * v0f[2];
    o0.w = p0 * vf[3] + p1 * v0f[3];
    o1.x = p0 * vf[4] + p1 * v0f[4];
    o1.y = p0 * vf[5] + p1 * v0f[5];
    o1.z = p0 * vf[6] + p1 * v0f[6];
    o1.w = p0 * vf[7] + p1 * v0f[7];
    ((float4*)cp)[0] = o0;
    ((float4*)cp)[1] = o1;

    if (l == 0) {
        float2 lp; lp.x = p0; lp.y = p1;
        ((float2*)(lat + ((size_t)bh * (S_ - 1) + (s - 1)) * 2))[0] = lp;
    }
}

// ------------------------------------------------- global-attention combine
// 64 blocks x 1 wave: block bh combines its NCH partials into ctx row s=0.
__global__ __launch_bounds__(64) void gcombine(const float* __restrict__ Pm,
                                               const float* __restrict__ Pl,
                                               const float* __restrict__ Po,
                                               float* __restrict__ ctx) {
    const int bh = blockIdx.x;
    const int b = bh >> 4, h = bh & 15;
    const int d = threadIdx.x;
    float ms = -1e30f;
#pragma unroll
    for (int c = 0; c < NCH; c++) ms = fmaxf(ms, Pm[bh * NCH + c]);
    float z = 0.f, o = 0.f;
#pragma unroll
    for (int c = 0; c < NCH; c++) {
        const float e = __expf(Pm[bh * NCH + c] - ms);
        z += Pl[bh * NCH + c] * e;
        o += Po[(size_t)(bh * NCH + c) * D_ + d] * e;
    }
    ctx[(size_t)b * S_ * H_ + (size_t)h * D_ + d] = o / z;
}

// ---------------------------------------------------------------- launcher
extern "C" void kernel_launch(void* const* d_in, const int* in_sizes, int n_in,
                              void* d_out, int out_size, void* d_ws, size_t ws_size,
                              hipStream_t stream) {
    const float* hs   = (const float*)d_in[0];
    const float* mask = (const float*)d_in[1];
    const float* Wq   = (const float*)d_in[2];
    const float* bq   = (const float*)d_in[3];
    const float* Wk   = (const float*)d_in[4];
    const float* bk   = (const float*)d_in[5];
    const float* Wv   = (const float*)d_in[6];
    const float* bv   = (const float*)d_in[7];

    float* out = (float*)d_out;                       // (B,S,H) fp32
    float* lat = out + (size_t)B_ * S_ * H_;          // (B,NH,S-1,1,2) fp32

    char* ws = (char*)d_ws;
    const size_t offXb  = 0;
    const size_t offWb  = offXb  + (size_t)M_TOT * K_TOT * 2;
    const size_t offQKV = offWb  + (size_t)3 * H_ * H_ * 2;
    const size_t offPm  = offQKV + (size_t)M_TOT * N_TOT * 2;
    const size_t offPl  = offPm  + (size_t)B_ * NH_ * NCH * 4;
    const size_t offPo  = offPl  + (size_t)B_ * NH_ * NCH * 4;

    unsigned short* Xb  = (unsigned short*)(ws + offXb);
    unsigned short* Wb  = (unsigned short*)(ws + offWb);
    unsigned short* QKV = (unsigned short*)(ws + offQKV);
    float* Pm = (float*)(ws + offPm);
    float* Pl = (float*)(ws + offPl);
    float* Po = (float*)(ws + offPo);

    const int total8 = M_TOT * K_TOT / 8 + 3 * H_ * H_ / 8;   // 2490368, /256 exact
    hipLaunchKernelGGL(cvt_all, dim3(total8 / 256), dim3(256), 0, stream,
                       hs, Wq, Wk, Wv, Xb, Wb);
    hipLaunchKernelGGL(gemm_qkv, dim3(12 * 64), dim3(512), 0, stream,
                       Xb, Wb, bq, bk, bv, QKV);
    hipLaunchKernelGGL(attn_fused, dim3(B_ * NH_, 144), dim3(256), 0, stream,
                       QKV, mask, out, lat, Pm, Pl, Po);
    hipLaunchKernelGGL(gcombine, dim3(B_ * NH_), dim3(64), 0, stream, Pm, Pl, Po, out);
}

// Round 8
// 287.674 us; speedup vs baseline: 1.0120x; 1.0102x over previous
//
#include <hip/hip_runtime.h>
#include <cstdint>
#include <cstddef>

// Problem constants
#define B_   4
#define S_   4096
#define H_   1024
#define NH_  16
#define D_   64
#define M_TOT (B_ * S_)    // 16384 rows of hidden
#define K_TOT H_           // 1024 reduction dim
#define N_TOT (3 * H_)     // 3072 = concat(Q,K,V) output cols
#define SCALE_ 0.125f      // 1/sqrt(64)
#define NCH 16             // chunks for global-attention online softmax
#define CH (S_ / NCH)      // 256 positions per chunk

typedef __bf16 bf16x8 __attribute__((ext_vector_type(8)));
typedef float  f32x4  __attribute__((ext_vector_type(4)));

__device__ __forceinline__ unsigned short f2b(float x) {
    unsigned int u = __float_as_uint(x);
    u += 0x7FFFu + ((u >> 16) & 1u);          // round-to-nearest-even
    return (unsigned short)(u >> 16);
}
__device__ __forceinline__ float b2f(unsigned int u) {   // u = bf16 bits in low 16
    return __uint_as_float(u << 16);
}
__device__ __forceinline__ void unp8(uint4 u, float* f) {
    f[0] = b2f(u.x & 0xffffu); f[1] = b2f(u.x >> 16);
    f[2] = b2f(u.y & 0xffffu); f[3] = b2f(u.y >> 16);
    f[4] = b2f(u.z & 0xffffu); f[5] = b2f(u.z >> 16);
    f[6] = b2f(u.w & 0xffffu); f[7] = b2f(u.w >> 16);
}
__device__ __forceinline__ unsigned int pack2(float lo, float hi) {
    return (unsigned int)f2b(lo) | ((unsigned int)f2b(hi) << 16);
}

// ------------------------------------------------- fused fp32->bf16 converts
__global__ __launch_bounds__(256) void cvt_all(const float* __restrict__ hs,
                                               const float* __restrict__ wq,
                                               const float* __restrict__ wk,
                                               const float* __restrict__ wv,
                                               unsigned short* __restrict__ Xb,
                                               unsigned short* __restrict__ Wb) {
    const int i = blockIdx.x * 256 + threadIdx.x;
    const int X8 = M_TOT * K_TOT / 8;          // 2097152 = 2^21
    const float4* sp;
    uint4* dp;
    int off;
    if (i < X8) {
        sp = (const float4*)hs;
        dp = (uint4*)Xb;
        off = i;
    } else {
        const int j = i - X8;
        const int w = j >> 17;                 // H*H/8 = 2^17
        off = j & 0x1ffff;
        sp = (const float4*)((w == 0) ? wq : (w == 1 ? wk : wv));
        dp = (uint4*)(Wb + (size_t)w * H_ * H_);
    }
    const float4 v0 = sp[off * 2];
    const float4 v1 = sp[off * 2 + 1];
    uint4 o;
    o.x = pack2(v0.x, v0.y);
    o.y = pack2(v0.z, v0.w);
    o.z = pack2(v1.x, v1.y);
    o.w = pack2(v1.z, v1.w);
    dp[off] = o;
}

// ---------------------------------------------------------------- QKV GEMM
// REVERTED verbatim to the R7/Round-3 16x16x32 kernel: 122.2 us measured,
// MfmaUtil 35%, SQ_LDS_BANK_CONFLICT = 0, = m248 reference (848 TF) for
// 256^2/K=1024. Both 32x32x16 ports hit an identical 9.4M-conflict signature
// (+4 cyc/ds_read) that two independent swizzle derivations failed to remove
// — that family is closed. GEMM is parked.
__global__ __launch_bounds__(512) void gemm_qkv(const unsigned short* __restrict__ A,
                                                const unsigned short* __restrict__ W,
                                                const float* __restrict__ bq,
                                                const float* __restrict__ bk,
                                                const float* __restrict__ bv,
                                                unsigned short* __restrict__ C) {
    __shared__ unsigned short Asl[2][256 * 64] __attribute__((aligned(16)));
    __shared__ unsigned short Bsl[2][256 * 64] __attribute__((aligned(16)));

    const int tid  = threadIdx.x;
    const int wid  = tid >> 6;
    const int lane = tid & 63;
    const int wm = wid >> 2, wn = wid & 3;     // 2 x 4 wave grid

    // XCD-aware bijective swizzle: 768 blocks = 8 XCDs x 96
    const int wg = (blockIdx.x & 7) * 96 + (blockIdx.x >> 3);
    const int bx = wg % 12;                    // N tile (3072/256)
    const int by = wg / 12;                    // M tile (16384/256)
    const int m0 = by * 256;
    const int n0 = bx * 256;

    // staging: one 8KB load = 64 rows x 128B; thread -> 16B slot; involution on k.
    const int srow = tid >> 3;
    const int gk = ((((tid >> 2) & 1) ^ ((tid >> 5) & 1)) << 5)
                 + (((tid & 3) ^ ((tid >> 3) & 3)) << 3);
    const size_t aG = (size_t)(m0 + srow) * K_TOT + gk;
    const size_t bG = (size_t)(n0 + srow) * K_TOT + gk;
    const int ldsW = wid << 9;                 // wave-uniform: rows wid*8 -> wid*8*64

    auto ST = [&](const unsigned short* g, unsigned short* l) {
        __builtin_amdgcn_global_load_lds((const __attribute__((address_space(1))) void*)g,
                                         (__attribute__((address_space(3))) void*)l, 16, 0, 0);
    };
    auto STAGE_A = [&](int t, int h) {         // half h of A K-tile t -> buf t&1
        unsigned short* l = &Asl[t & 1][(h << 13) + ldsW];
        const unsigned short* g = A + aG + ((size_t)(h << 7)) * K_TOT + (size_t)t * 64;
        ST(g, l);
        ST(g + (size_t)64 * K_TOT, l + 4096);
    };
    auto STAGE_B = [&](int t, int h) {
        unsigned short* l = &Bsl[t & 1][(h << 13) + ldsW];
        const unsigned short* g = W + bG + ((size_t)(h << 7)) * K_TOT + (size_t)t * 64;
        ST(g, l);
        ST(g + (size_t)64 * K_TOT, l + 4096);
    };

    // fragment-read constants (inverse involution)
    const int rl   = lane & 15;
    const int chsw = (((lane >> 4) ^ (rl & 3)) << 3);   // swizzled 16B chunk (elems)
    const int ko0  = ((rl >> 2) & 1) << 5;              // k-half slot holding kk=0
    const int ko1  = ko0 ^ 32;
    const int aro  = (wm * 128 + rl) * 64 + chsw;
    const int bro  = (wn * 64 + rl) * 64 + chsw;

    f32x4 acc[8][4];
#pragma unroll
    for (int i = 0; i < 8; i++)
#pragma unroll
        for (int j = 0; j < 4; j++) acc[i][j] = (f32x4){0.f, 0.f, 0.f, 0.f};

    // one K=64 tile, 4 phases, NO sched_barrier pins (m141 lesson)
    auto TILE = [&](int t, bool stD0, bool stD23, int vm) {
        const unsigned short* Ab = Asl[t & 1];
        const unsigned short* Bb = Bsl[t & 1];
        bf16x8 a0[4][2], a1[4][2], b0[2][2], b1[2][2];
        // ---------- d0: 12 reads + stage A1(t+1) + MFMA (mi0-3 x ni0-1)
#pragma unroll
        for (int mi = 0; mi < 4; mi++) {
            a0[mi][0] = *(const bf16x8*)&Ab[aro + mi * 1024 + ko0];
            a0[mi][1] = *(const bf16x8*)&Ab[aro + mi * 1024 + ko1];
        }
#pragma unroll
        for (int ni = 0; ni < 2; ni++) {
            b0[ni][0] = *(const bf16x8*)&Bb[bro + ni * 1024 + ko0];
            b0[ni][1] = *(const bf16x8*)&Bb[bro + ni * 1024 + ko1];
        }
        if (stD0) STAGE_A(t + 1, 1);
        __builtin_amdgcn_s_barrier();
        asm volatile("s_waitcnt lgkmcnt(0)" ::: "memory");
        __builtin_amdgcn_s_setprio(1);
#pragma unroll
        for (int mi = 0; mi < 4; mi++)
#pragma unroll
            for (int ni = 0; ni < 2; ni++)
#pragma unroll
                for (int kk = 0; kk < 2; kk++)
                    acc[mi][ni] = __builtin_amdgcn_mfma_f32_16x16x32_bf16(a0[mi][kk], b0[ni][kk], acc[mi][ni], 0, 0, 0);
        __builtin_amdgcn_s_setprio(0);
        __builtin_amdgcn_s_barrier();
        // ---------- d1: 4 reads (B ni2-3) + MFMA (mi0-3 x ni2-3)
#pragma unroll
        for (int ni = 0; ni < 2; ni++) {
            b1[ni][0] = *(const bf16x8*)&Bb[bro + (ni + 2) * 1024 + ko0];
            b1[ni][1] = *(const bf16x8*)&Bb[bro + (ni + 2) * 1024 + ko1];
        }
        __builtin_amdgcn_s_barrier();
        asm volatile("s_waitcnt lgkmcnt(0)" ::: "memory");
        __builtin_amdgcn_s_setprio(1);
#pragma unroll
        for (int mi = 0; mi < 4; mi++)
#pragma unroll
            for (int ni = 0; ni < 2; ni++)
#pragma unroll
                for (int kk = 0; kk < 2; kk++)
                    acc[mi][ni + 2] = __builtin_amdgcn_mfma_f32_16x16x32_bf16(a0[mi][kk], b1[ni][kk], acc[mi][ni + 2], 0, 0, 0);
        __builtin_amdgcn_s_setprio(0);
        __builtin_amdgcn_s_barrier();
        // ---------- d2: 8 reads (A mi4-7) + stage B0,B1(t+2) + MFMA (mi4-7 x ni2-3)
#pragma unroll
        for (int mi = 0; mi < 4; mi++) {
            a1[mi][0] = *(const bf16x8*)&Ab[aro + (mi + 4) * 1024 + ko0];
            a1[mi][1] = *(const bf16x8*)&Ab[aro + (mi + 4) * 1024 + ko1];
        }
        if (stD23) { STAGE_B(t + 2, 0); STAGE_B(t + 2, 1); }
        __builtin_amdgcn_s_barrier();
        asm volatile("s_waitcnt lgkmcnt(0)" ::: "memory");
        __builtin_amdgcn_s_setprio(1);
#pragma unroll
        for (int mi = 0; mi < 4; mi++)
#pragma unroll
            for (int ni = 0; ni < 2; ni++)
#pragma unroll
                for (int kk = 0; kk < 2; kk++)
                    acc[mi + 4][ni + 2] = __builtin_amdgcn_mfma_f32_16x16x32_bf16(a1[mi][kk], b1[ni][kk], acc[mi + 4][ni + 2], 0, 0, 0);
        __builtin_amdgcn_s_setprio(0);
        __builtin_amdgcn_s_barrier();
        // ---------- d3: stage A0(t+2) + MFMA (mi4-7 x ni0-1) + boundary vmcnt
        if (stD23) STAGE_A(t + 2, 0);
        __builtin_amdgcn_s_barrier();
        __builtin_amdgcn_s_setprio(1);
#pragma unroll
        for (int mi = 0; mi < 4; mi++)
#pragma unroll
            for (int ni = 0; ni < 2; ni++)
#pragma unroll
                for (int kk = 0; kk < 2; kk++)
                    acc[mi + 4][ni] = __builtin_amdgcn_mfma_f32_16x16x32_bf16(a1[mi][kk], b0[ni][kk], acc[mi + 4][ni], 0, 0, 0);
        __builtin_amdgcn_s_setprio(0);
        if (vm == 6)      asm volatile("s_waitcnt vmcnt(6)" ::: "memory");
        else if (vm == 0) asm volatile("s_waitcnt vmcnt(0)" ::: "memory");
        if (vm >= 0) __builtin_amdgcn_s_barrier();
    };

    // prologue: tile 0 complete (8 loads) + B0(1),B1(1),A0(1) (6 loads);
    // vmcnt(6) retires exactly the oldest 8 = tile 0. A1(1) staged at d0 of tile 0.
    STAGE_A(0, 0); STAGE_A(0, 1); STAGE_B(0, 0); STAGE_B(0, 1);
    STAGE_B(1, 0); STAGE_B(1, 1); STAGE_A(1, 0);
    asm volatile("s_waitcnt vmcnt(6)" ::: "memory");
    __builtin_amdgcn_s_barrier();

    // 16 K-tiles: 14 full + 2 tail. Unroll-2 makes buf index t&1 compile-time.
#pragma unroll 1
    for (int tt = 0; tt < 14; tt += 2) {
        TILE(tt,     true, true, 6);
        TILE(tt + 1, true, true, 6);
    }
    TILE(14, true,  false, 0);   // stages A1(15); drain all before last tile
    TILE(15, false, false, -1);

    // C write + bias (verified fragment->(row,col) convention)
    const int col_l = lane & 15;
    const int quad  = lane >> 4;
#pragma unroll
    for (int mi = 0; mi < 8; mi++) {
#pragma unroll
        for (int ni = 0; ni < 4; ni++) {
            const int gc = n0 + wn * 64 + ni * 16 + col_l;
            const float bias = (gc < H_) ? bq[gc] : (gc < 2 * H_ ? bk[gc - H_] : bv[gc - 2 * H_]);
#pragma unroll
            for (int i = 0; i < 4; i++) {
                const int gr = m0 + wm * 128 + mi * 16 + quad * 4 + i;
                C[(size_t)gr * N_TOT + gc] = f2b(acc[mi][ni][i] + bias);
            }
        }
    }
}

// ------------------------------------------------- fused attention, round 11
// 1-D grid, 9216 blocks x 256 thr:
//   blk <  8192 : local attention, ONE BLOCK PER 2 (b,s) ROWS covering ALL 16
//                 heads. Thread t: s_off=t>>7, h=(t>>3)&15, l=t&7. Each
//                 128-thread group reads q/k/v as CONTIGUOUS 2KB spans (was
//                 128B scattered segments per 8-lane group) and writes ctx as
//                 one contiguous 4KB fp32 row. Same math as before.
//   blk >= 8192 : global-attention chunk (c=blk-8192: bh=c>>4, chunk=c&15),
//                 body identical to the verified R5/R6 version.
__global__ __launch_bounds__(256) void attn_fused(const unsigned short* __restrict__ QKV,
                                                  const float* __restrict__ mask,
                                                  float* __restrict__ ctx,
                                                  float* __restrict__ lat,
                                                  float* __restrict__ Pm,
                                                  float* __restrict__ Pl,
                                                  float* __restrict__ Po) {
    const int blk = blockIdx.x;

    if (blk >= 8192) {
        // ------------------------------ global attention partial (one chunk)
        const int c = blk - 8192;
        const int bh = c >> 4;
        const int chunk = c & 15;
        const int b = bh >> 4, h = bh & 15;
        const int tid = threadIdx.x;
        const int w = tid >> 6, lane = tid & 63;

        __shared__ float gq_sh[D_];
        __shared__ float pr[CH];
        __shared__ float red[8];
        __shared__ float osum[4][D_];

        const unsigned short* gqp = QKV + (size_t)(b * S_) * N_TOT + h * D_;
        if (tid < D_) gq_sh[tid] = b2f(gqp[tid]);
        __syncthreads();

        const int s0 = chunk * CH;
        const int s  = s0 + tid;
        const uint4* kp4 = (const uint4*)(QKV + (size_t)(b * S_ + s) * N_TOT + H_ + h * D_);
        float acc = 0.f;
#pragma unroll
        for (int cc = 0; cc < 8; cc++) {
            uint4 r = kp4[cc];
            acc += b2f(r.x & 0xffffu) * gq_sh[cc * 8 + 0];
            acc += b2f(r.x >> 16)     * gq_sh[cc * 8 + 1];
            acc += b2f(r.y & 0xffffu) * gq_sh[cc * 8 + 2];
            acc += b2f(r.y >> 16)     * gq_sh[cc * 8 + 3];
            acc += b2f(r.z & 0xffffu) * gq_sh[cc * 8 + 4];
            acc += b2f(r.z >> 16)     * gq_sh[cc * 8 + 5];
            acc += b2f(r.w & 0xffffu) * gq_sh[cc * 8 + 6];
            acc += b2f(r.w >> 16)     * gq_sh[cc * 8 + 7];
        }
        const float sv = acc * SCALE_ + mask[b * S_ + s];

        float wmax = sv;
#pragma unroll
        for (int m = 32; m >= 1; m >>= 1) wmax = fmaxf(wmax, __shfl_xor(wmax, m, 64));
        if (lane == 0) red[w] = wmax;
        __syncthreads();
        const float bmax = fmaxf(fmaxf(red[0], red[1]), fmaxf(red[2], red[3]));

        const float p = __expf(sv - bmax);
        pr[tid] = p;
        float wsum = p;
#pragma unroll
        for (int m = 32; m >= 1; m >>= 1) wsum += __shfl_xor(wsum, m, 64);
        if (lane == 0) red[4 + w] = wsum;
        __syncthreads();   // publishes pr[] for phase 2
        const float bsum = red[4] + red[5] + red[6] + red[7];

        const int g = lane >> 3;
        const int l = lane & 7;
        float o8[8];
#pragma unroll
        for (int j = 0; j < 8; j++) o8[j] = 0.f;
        const int sbase = s0 + w * 64;
#pragma unroll
        for (int i = 0; i < 8; i++) {
            const int si = sbase + i * 8 + g;
            const uint4 vu = *(const uint4*)(QKV + (size_t)(b * S_ + si) * N_TOT + 2 * H_ + h * D_ + l * 8);
            float vf[8];
            unp8(vu, vf);
            const float pw = pr[w * 64 + i * 8 + g];
#pragma unroll
            for (int j = 0; j < 8; j++) o8[j] += pw * vf[j];
        }
#pragma unroll
        for (int j = 0; j < 8; j++) {
            o8[j] += __shfl_xor(o8[j], 8, 64);
            o8[j] += __shfl_xor(o8[j], 16, 64);
            o8[j] += __shfl_xor(o8[j], 32, 64);
        }
        if (g == 0) {
#pragma unroll
            for (int j = 0; j < 8; j++) osum[w][l * 8 + j] = o8[j];
        }
        __syncthreads();
        if (tid < D_) {
            const float ot = osum[0][tid] + osum[1][tid] + osum[2][tid] + osum[3][tid];
            Po[(size_t)(bh * NCH + chunk) * D_ + tid] = ot;
            if (tid == 0) {
                Pm[bh * NCH + chunk] = bmax;
                Pl[bh * NCH + chunk] = bsum;
            }
        }
        return;
    }

    // ------------------------------ local attention: 2 full (b,s) rows/block
    const int t = threadIdx.x;
    const int r = blk * 2 + (t >> 7);          // global row id, 0..16383
    const int b = r >> 12;                     // 4096 rows per batch
    const int s = r & 4095;
    if (s == 0) return;                        // s=0 handled by global attention

    const int h = (t >> 3) & 15;
    const int l = t & 7;
    const int bh = (b << 4) + h;

    const size_t rowS = (size_t)(b * S_ + s) * N_TOT + h * D_ + l * 8;
    const size_t row0 = (size_t)(b * S_) * N_TOT + h * D_ + l * 8;

    uint4 qu  = *(const uint4*)(QKV + rowS);
    uint4 ku  = *(const uint4*)(QKV + rowS + H_);
    uint4 k0u = *(const uint4*)(QKV + row0 + H_);
    float qf[8], kf[8], k0f[8];
    unp8(qu, qf); unp8(ku, kf); unp8(k0u, k0f);

    float ps = 0.f, pg = 0.f;
#pragma unroll
    for (int i = 0; i < 8; i++) { ps += qf[i] * kf[i]; pg += qf[i] * k0f[i]; }
#pragma unroll
    for (int m = 1; m < 8; m <<= 1) {   // reduce within the 8-lane d-group
        ps += __shfl_xor(ps, m, 64);
        pg += __shfl_xor(pg, m, 64);
    }
    ps *= SCALE_; pg *= SCALE_;
    const float mx = fmaxf(ps, pg);
    const float e0 = __expf(ps - mx), e1 = __expf(pg - mx);
    const float z = e0 + e1;
    const float p0 = e0 / z, p1 = e1 / z;

    uint4 vu  = *(const uint4*)(QKV + rowS + 2 * H_);
    uint4 v0u = *(const uint4*)(QKV + row0 + 2 * H_);
    float vf[8], v0f[8];
    unp8(vu, vf); unp8(v0u, v0f);

    float* cp = ctx + (size_t)b * (S_ * H_) + (size_t)s * H_ + h * D_ + l * 8;
    float4 o0, o1;
    o0.x = p0 * vf[0] + p1 * v0f[0];
    o0.y = p0 * vf[1] + p1 * v0f[1];
    o0.z = p0 * vf[2] + p1 * v0f[2];
    o0.w = p0 * vf[3] + p1 * v0f[3];
    o1.x = p0 * vf[4] + p1 * v0f[4];
    o1.y = p0 * vf[5] + p1 * v0f[5];
    o1.z = p0 * vf[6] + p1 * v0f[6];
    o1.w = p0 * vf[7] + p1 * v0f[7];
    ((float4*)cp)[0] = o0;
    ((float4*)cp)[1] = o1;

    if (l == 0) {
        float2 lp; lp.x = p0; lp.y = p1;
        ((float2*)(lat + ((size_t)bh * (S_ - 1) + (s - 1)) * 2))[0] = lp;
    }
}

// ------------------------------------------------- global-attention combine
// 64 blocks x 1 wave: block bh combines its NCH partials into ctx row s=0.
__global__ __launch_bounds__(64) void gcombine(const float* __restrict__ Pm,
                                               const float* __restrict__ Pl,
                                               const float* __restrict__ Po,
                                               float* __restrict__ ctx) {
    const int bh = blockIdx.x;
    const int b = bh >> 4, h = bh & 15;
    const int d = threadIdx.x;
    float ms = -1e30f;
#pragma unroll
    for (int c = 0; c < NCH; c++) ms = fmaxf(ms, Pm[bh * NCH + c]);
    float z = 0.f, o = 0.f;
#pragma unroll
    for (int c = 0; c < NCH; c++) {
        const float e = __expf(Pm[bh * NCH + c] - ms);
        z += Pl[bh * NCH + c] * e;
        o += Po[(size_t)(bh * NCH + c) * D_ + d] * e;
    }
    ctx[(size_t)b * S_ * H_ + (size_t)h * D_ + d] = o / z;
}

// ---------------------------------------------------------------- launcher
extern "C" void kernel_launch(void* const* d_in, const int* in_sizes, int n_in,
                              void* d_out, int out_size, void* d_ws, size_t ws_size,
                              hipStream_t stream) {
    const float* hs   = (const float*)d_in[0];
    const float* mask = (const float*)d_in[1];
    const float* Wq   = (const float*)d_in[2];
    const float* bq   = (const float*)d_in[3];
    const float* Wk   = (const float*)d_in[4];
    const float* bk   = (const float*)d_in[5];
    const float* Wv   = (const float*)d_in[6];
    const float* bv   = (const float*)d_in[7];

    float* out = (float*)d_out;                       // (B,S,H) fp32
    float* lat = out + (size_t)B_ * S_ * H_;          // (B,NH,S-1,1,2) fp32

    char* ws = (char*)d_ws;
    const size_t offXb  = 0;
    const size_t offWb  = offXb  + (size_t)M_TOT * K_TOT * 2;
    const size_t offQKV = offWb  + (size_t)3 * H_ * H_ * 2;
    const size_t offPm  = offQKV + (size_t)M_TOT * N_TOT * 2;
    const size_t offPl  = offPm  + (size_t)B_ * NH_ * NCH * 4;
    const size_t offPo  = offPl  + (size_t)B_ * NH_ * NCH * 4;

    unsigned short* Xb  = (unsigned short*)(ws + offXb);
    unsigned short* Wb  = (unsigned short*)(ws + offWb);
    unsigned short* QKV = (unsigned short*)(ws + offQKV);
    float* Pm = (float*)(ws + offPm);
    float* Pl = (float*)(ws + offPl);
    float* Po = (float*)(ws + offPo);

    const int total8 = M_TOT * K_TOT / 8 + 3 * H_ * H_ / 8;   // 2490368, /256 exact
    hipLaunchKernelGGL(cvt_all, dim3(total8 / 256), dim3(256), 0, stream,
                       hs, Wq, Wk, Wv, Xb, Wb);
    hipLaunchKernelGGL(gemm_qkv, dim3(12 * 64), dim3(512), 0, stream,
                       Xb, Wb, bq, bk, bv, QKV);
    hipLaunchKernelGGL(attn_fused, dim3(8192 + 1024), dim3(256), 0, stream,
                       QKV, mask, out, lat, Pm, Pl, Po);
    hipLaunchKernelGGL(gcombine, dim3(B_ * NH_), dim3(64), 0, stream, Pm, Pl, Po, out);
}